// Round 3
// baseline (378.635 us; speedup 1.0000x reference)
//
#include <hip/hip_runtime.h>

typedef float v4 __attribute__((ext_vector_type(4)));
typedef float v2 __attribute__((ext_vector_type(2)));

#define D_MODEL 1024
#define D_STATE 64
#define CHUNK   256

// Grid: 512 blocks = 64 bc-chunks x 8 d-slices (128 d). Block 256 thr = 4 waves
// -> 2 blocks/CU, 8 waves/CU (2/SIMD).
// Thread: ng = tid&3 owns n in [ng*16,ng*16+16); dp = tid>>2 owns d-pair
// d = dsl*128 + dp*2. h,a: 16 x 2 floats in VGPRs.
// B/C: NO LDS. Rows are 256 B, L1-resident (read by all d-threads of the bc).
// Global dwordx4 loads, ping-pong prefetched 1 t ahead in registers: traffic
// moves from the saturated LDS pipe (1536 cyc/CU/t at d_t=1) to the idle
// VMEM/L1 pipe (~320 cyc/CU/t). Zero barriers.
// y: quad butterfly shfl_xor(1,2) over the 4 n-groups; ng==0 lanes store v2.
__global__ __launch_bounds__(256, 2)
void YvParallelScan_kernel(const float* __restrict__ u,
                           const float* __restrict__ B,
                           const float* __restrict__ C,
                           const float* __restrict__ A_log,
                           float* __restrict__ out) {
    const int bid = blockIdx.x;
    const int bc  = bid >> 3;          // 0..63  (batch*chunk index)
    const int dsl = bid & 7;           // d-slice (128 d each)
    const int tid = threadIdx.x;
    const int ng  = tid & 3;           // n-group within quad
    const int dp  = tid >> 2;          // 0..63: d-pair within slice
    const int d   = dsl * 128 + dp * 2;
    const int rowbase = bc * CHUNK;

    float a0[16], a1[16], h0[16], h1[16];
#pragma unroll
    for (int j = 0; j < 16; ++j) {
        const int n = ng * 16 + j;
        v2 al = *(const v2*)(A_log + (size_t)n * D_MODEL + d);
        a0[j] = -__expf(al[0]);
        a1[j] = -__expf(al[1]);
        h0[j] = 0.f; h1[j] = 0.f;
    }

    const v4* Bg = (const v4*)(B + (size_t)rowbase * D_STATE) + ng * 4;
    const v4* Cg = (const v4*)(C + (size_t)rowbase * D_STATE) + ng * 4;
    const float* uptr = u   + (size_t)rowbase * D_MODEL + d;
    float*       optr = out + (size_t)rowbase * D_MODEL + d;

    // x prefetch depth 2 (covers HBM stream latency)
    v2 x0 = *(const v2*)(uptr);
    v2 x1 = *(const v2*)(uptr + D_MODEL);

    // B/C ping-pong register buffers, prefetch depth 1 (L1-hit latency)
    v4 bA[4], cA[4], bB[4], cB[4];
#pragma unroll
    for (int jj = 0; jj < 4; ++jj) { bA[jj] = Bg[jj]; cA[jj] = Cg[jj]; }

    for (int t = 0; t < CHUNK; t += 2) {
        // ---------- even step: consume bA/cA (t), prefetch bB/cB (t+1)
        {
#pragma unroll
            for (int jj = 0; jj < 4; ++jj) {
                bB[jj] = Bg[(size_t)(t + 1) * 16 + jj];
                cB[jj] = Cg[(size_t)(t + 1) * 16 + jj];
            }
            const int tp = (t + 2 < CHUNK) ? t + 2 : CHUNK - 1;
            const v2 xn = *(const v2*)(uptr + (size_t)tp * D_MODEL);

            float acc0 = 0.f, acc1 = 0.f;
#pragma unroll
            for (int jj = 0; jj < 4; ++jj) {
                const v4 b = bA[jj], c = cA[jj];
#pragma unroll
                for (int k = 0; k < 4; ++k) {
                    const int j = jj * 4 + k;
                    h0[j] = a0[j] * h0[j] + b[k] * x0[0];
                    h1[j] = a1[j] * h1[j] + b[k] * x0[1];
                    acc0 += c[k] * h0[j];
                    acc1 += c[k] * h1[j];
                }
            }
            acc0 += __shfl_xor(acc0, 1); acc0 += __shfl_xor(acc0, 2);
            acc1 += __shfl_xor(acc1, 1); acc1 += __shfl_xor(acc1, 2);
            if (ng == 0) {
                v2 o; o[0] = acc0; o[1] = acc1;
                *(v2*)(optr + (size_t)t * D_MODEL) = o;
            }
            x0 = x1; x1 = xn;
        }
        // ---------- odd step: consume bB/cB (t+1), prefetch bA/cA (t+2)
        {
            const int tn = (t + 2 < CHUNK) ? t + 2 : CHUNK - 1;
#pragma unroll
            for (int jj = 0; jj < 4; ++jj) {
                bA[jj] = Bg[(size_t)tn * 16 + jj];
                cA[jj] = Cg[(size_t)tn * 16 + jj];
            }
            const int tp = (t + 3 < CHUNK) ? t + 3 : CHUNK - 1;
            const v2 xn = *(const v2*)(uptr + (size_t)tp * D_MODEL);

            float acc0 = 0.f, acc1 = 0.f;
#pragma unroll
            for (int jj = 0; jj < 4; ++jj) {
                const v4 b = bB[jj], c = cB[jj];
#pragma unroll
                for (int k = 0; k < 4; ++k) {
                    const int j = jj * 4 + k;
                    h0[j] = a0[j] * h0[j] + b[k] * x0[0];
                    h1[j] = a1[j] * h1[j] + b[k] * x0[1];
                    acc0 += c[k] * h0[j];
                    acc1 += c[k] * h1[j];
                }
            }
            acc0 += __shfl_xor(acc0, 1); acc0 += __shfl_xor(acc0, 2);
            acc1 += __shfl_xor(acc1, 1); acc1 += __shfl_xor(acc1, 2);
            if (ng == 0) {
                v2 o; o[0] = acc0; o[1] = acc1;
                *(v2*)(optr + (size_t)(t + 1) * D_MODEL) = o;
            }
            x0 = x1; x1 = xn;
        }
    }
}

extern "C" void kernel_launch(void* const* d_in, const int* in_sizes, int n_in,
                              void* d_out, int out_size, void* d_ws, size_t ws_size,
                              hipStream_t stream) {
    const float* u     = (const float*)d_in[0];
    // d_in[1] = delta, unused by the reference forward
    const float* B     = (const float*)d_in[2];
    const float* C     = (const float*)d_in[3];
    const float* A_log = (const float*)d_in[4];
    float* out = (float*)d_out;

    YvParallelScan_kernel<<<512, 256, 0, stream>>>(u, B, C, A_log, out);
}

// Round 5
// 249.723 us; speedup vs baseline: 1.5162x; 1.5162x over previous
//
#include <hip/hip_runtime.h>

typedef float v4 __attribute__((ext_vector_type(4)));
typedef float v2 __attribute__((ext_vector_type(2)));

#define D_MODEL 1024
#define D_STATE 64
#define CHUNK   256
#define TILE_T  64

// Grid: 512 blocks = 64 bc-chunks x 8 d-slices (128 d each). Block 256 thr =
// 4 waves -> 2 blocks/CU (128 KB LDS), 8 waves/CU, 2 waves/SIMD.
// Thread: ng = tid&3 owns n in [ng*16, ng*16+16); dp = tid>>2 owns d-pair.
// h,a: 16 x 2 floats in VGPRs (d_t=2 halves LDS instrs/CU/t vs R2: 64 vs 128).
// B/C: LDS double-buffered 64-t tiles (R3 proved per-t global loads cannot be
// software-pipelined at HIP level - compiler sinks them). 8 ds_read_b128
// broadcast reads per thread per t; staging = reg-staged, 1 barrier / 64 t.
// y-reduction: v_add_f32 + DPP quad_perm (VALU pipe!) replaces shfl_xor's
// ds_swizzle - keeps the reduction OFF the LDS pipe (R2's co-bottleneck).
// NOTE: dpp_ctrl must be an ICE at the builtin call site -> template param.
template <int CTRL>
__device__ __forceinline__ float quad_xor_add(float v) {
    int p = __builtin_amdgcn_update_dpp(
        0, __builtin_bit_cast(int, v), CTRL, 0xF, 0xF, true);
    return v + __builtin_bit_cast(float, p);
}

__global__ __launch_bounds__(256, 2)
void YvParallelScan_kernel(const float* __restrict__ u,
                           const float* __restrict__ B,
                           const float* __restrict__ C,
                           const float* __restrict__ A_log,
                           float* __restrict__ out) {
    __shared__ v4 sB[2][TILE_T * 16];   // [buf][tl][n/4]  16 KB each
    __shared__ v4 sC[2][TILE_T * 16];

    const int bid = blockIdx.x;
    const int bc  = bid >> 3;          // 0..63  (batch*chunk index)
    const int dsl = bid & 7;           // d-slice (128 d each)
    const int tid = threadIdx.x;
    const int ng  = tid & 3;           // n-group within quad (lanes 4k..4k+3)
    const int dp  = tid >> 2;          // 0..63: d-pair within slice
    const int d   = dsl * 128 + dp * 2;
    const int rowbase = bc * CHUNK;

    float a0[16], a1[16], h0[16], h1[16];
#pragma unroll
    for (int j = 0; j < 16; ++j) {
        const int n = ng * 16 + j;
        v2 al = *(const v2*)(A_log + (size_t)n * D_MODEL + d);
        a0[j] = -__expf(al[0]);
        a1[j] = -__expf(al[1]);
        h0[j] = 0.f; h1[j] = 0.f;
    }

    const v4* Bg = (const v4*)(B + (size_t)rowbase * D_STATE);
    const v4* Cg = (const v4*)(C + (size_t)rowbase * D_STATE);
    const float* uptr = u   + (size_t)rowbase * D_MODEL + d;
    float*       optr = out + (size_t)rowbase * D_MODEL + d;

    // prologue: stage tile 0 into buf 0
    v4 rb[4], rc[4];
#pragma unroll
    for (int k = 0; k < 4; ++k) {
        rb[k] = Bg[k * 256 + tid];
        rc[k] = Cg[k * 256 + tid];
    }
#pragma unroll
    for (int k = 0; k < 4; ++k) {
        sB[0][k * 256 + tid] = rb[k];
        sC[0][k * 256 + tid] = rc[k];
    }

    // x prefetch depth 2 (proven pattern from R2)
    v2 x0 = *(const v2*)(uptr);
    v2 x1 = *(const v2*)(uptr + D_MODEL);

    __syncthreads();

    for (int ti = 0; ti < CHUNK / TILE_T; ++ti) {
        const int cur = ti & 1;

        // issue next tile's global loads early; even if the compiler sinks
        // them to the ds_write below, the stall is once per 64 t (harmless)
        if (ti < CHUNK / TILE_T - 1) {
#pragma unroll
            for (int k = 0; k < 4; ++k) {
                rb[k] = Bg[(ti + 1) * 1024 + k * 256 + tid];
                rc[k] = Cg[(ti + 1) * 1024 + k * 256 + tid];
            }
        }

#pragma unroll 4
        for (int tl = 0; tl < TILE_T; ++tl) {
            const int t  = ti * TILE_T + tl;
            const int tp = (t + 2 < CHUNK) ? t + 2 : CHUNK - 1;
            const v2 xn = *(const v2*)(uptr + (size_t)tp * D_MODEL);

            float accE0 = 0.f, accO0 = 0.f, accE1 = 0.f, accO1 = 0.f;
#pragma unroll
            for (int jj = 0; jj < 4; ++jj) {
                const v4 b = sB[cur][tl * 16 + ng * 4 + jj];  // broadcast b128
                const v4 c = sC[cur][tl * 16 + ng * 4 + jj];
#pragma unroll
                for (int k = 0; k < 4; ++k) {
                    const int j = jj * 4 + k;
                    h0[j] = a0[j] * h0[j] + b[k] * x0[0];
                    h1[j] = a1[j] * h1[j] + b[k] * x0[1];
                    if (k & 1) { accO0 += c[k] * h0[j]; accO1 += c[k] * h1[j]; }
                    else       { accE0 += c[k] * h0[j]; accE1 += c[k] * h1[j]; }
                }
            }
            float acc0 = accE0 + accO0;
            float acc1 = accE1 + accO1;
            // quad butterfly over 4 n-groups on the VALU pipe (DPP quad_perm)
            acc0 = quad_xor_add<0xB1>(acc0);  // xor 1: [1,0,3,2]
            acc0 = quad_xor_add<0x4E>(acc0);  // xor 2: [2,3,0,1]
            acc1 = quad_xor_add<0xB1>(acc1);
            acc1 = quad_xor_add<0x4E>(acc1);
            if (ng == 0) {
                v2 o; o[0] = acc0; o[1] = acc1;
                *(v2*)(optr + (size_t)t * D_MODEL) = o;
            }
            x0 = x1; x1 = xn;
        }

        // write next tile into the other buffer; single barrier per tile
        if (ti < CHUNK / TILE_T - 1) {
#pragma unroll
            for (int k = 0; k < 4; ++k) {
                sB[cur ^ 1][k * 256 + tid] = rb[k];
                sC[cur ^ 1][k * 256 + tid] = rc[k];
            }
        }
        __syncthreads();
    }
}

extern "C" void kernel_launch(void* const* d_in, const int* in_sizes, int n_in,
                              void* d_out, int out_size, void* d_ws, size_t ws_size,
                              hipStream_t stream) {
    const float* u     = (const float*)d_in[0];
    // d_in[1] = delta, unused by the reference forward
    const float* B     = (const float*)d_in[2];
    const float* C     = (const float*)d_in[3];
    const float* A_log = (const float*)d_in[4];
    float* out = (float*)d_out;

    YvParallelScan_kernel<<<512, 256, 0, stream>>>(u, B, C, A_log, out);
}